// Round 3
// baseline (246.451 us; speedup 1.0000x reference)
//
#include <hip/hip_runtime.h>
#include <hip/hip_bf16.h>
#include <math.h>

#define NV 6890   // SMPL vertex count
#define NC 1024   // contact vertices

// ---------------------------------------------------------------------------
// Single compute kernel: one block per contact row i (1024 blocks x 256 thr).
//
// - geomask storage mode (int32 words vs raw bool bytes) detected by wave 0
//   via ballot over the first 64 words (4-byte storage => every word in
//   {0,1,0x3F800000}; random packed bool bytes essentially never are).
// - 1024 contact coords staged in LDS (16 KB).
// - Full geomask row vi read COALESCED into LDS bytes (6.9 KB byte-mode /
//   27.5 KB word-mode); the 1024 mask lookups gather from LDS, not global.
// - Lexicographic (score, idx) min == jnp.argmin semantics (first tie,
//   all-inf -> 0). argmin over masked d^2 == argmin over masked (d+1).
//   Distance recomputed at the winner (all-masked row -> d(i, pc[0])).
// - Per-row tanh contribution accumulated straight into d_out via one
//   atomicAdd per block (d_out zeroed by a 4-byte memset beforehand).
//   1024-term float atomic sum: error ~1e-6, threshold 2.9e-3.
// ---------------------------------------------------------------------------
__global__ __launch_bounds__(256) void contact_row_kernel(
        const int* __restrict__ pc, const float* __restrict__ verts,
        const void* __restrict__ gm, float* __restrict__ out) {
    __shared__ float sx[NC], sy[NC], sz[NC];
    __shared__ int   spc[NC];
    __shared__ unsigned char rowm[NV];
    __shared__ int   modeSh;
    __shared__ float wbest[4];
    __shared__ int   widx[4];

    const int tid = threadIdx.x;

    // --- storage-mode detection (wave 0, one coalesced 256B load) ---
    if (tid < 64) {
        unsigned int w = ((const unsigned int*)gm)[tid];
        bool ok4 = (w == 0u || w == 1u || w == 0x3F800000u);
        unsigned long long b = __ballot(ok4);
        if (tid == 0) modeSh = (b == ~0ULL) ? 0 : 1;  // 0: 4-byte words, 1: bytes
    }

    // --- stage contact vertex coords ---
    for (int j = tid; j < NC; j += 256) {
        int v = pc[j];
        spc[j] = v;
        sx[j] = verts[3 * v + 0];
        sy[j] = verts[3 * v + 1];
        sz[j] = verts[3 * v + 2];
    }
    __syncthreads();

    const int i  = blockIdx.x;
    const int vi = spc[i];

    // --- stage geomask row vi into LDS as bytes, coalesced ---
    if (modeSh == 0) {
        const unsigned int* row = (const unsigned int*)gm + (size_t)vi * NV;
        for (int k = tid; k < NV; k += 256) rowm[k] = (unsigned char)(row[k] != 0u);
    } else {
        const unsigned char* row = (const unsigned char*)gm + (size_t)vi * NV;
        for (int k = tid; k < NV; k += 256) rowm[k] = row[k];
    }
    __syncthreads();

    const float xi = sx[i], yi = sy[i], zi = sz[i];
    float best = INFINITY;
    int   bidx = 0x7FFFFFFF;
    #pragma unroll
    for (int u = 0; u < NC / 256; ++u) {
        int j = tid + u * 256;
        float dx = xi - sx[j], dy = yi - sy[j], dz = zi - sz[j];
        float d2 = dx * dx + dy * dy + dz * dz;
        float s = rowm[spc[j]] ? d2 : INFINITY;
        if (s < best || (s == best && j < bidx)) { best = s; bidx = j; }
    }

    // --- wave (64-lane) argmin reduction, then cross-wave via LDS ---
    #pragma unroll
    for (int off = 32; off > 0; off >>= 1) {
        float ob = __shfl_down(best, off, 64);
        int   oi = __shfl_down(bidx, off, 64);
        if (ob < best || (ob == best && oi < bidx)) { best = ob; bidx = oi; }
    }
    if ((tid & 63) == 0) { wbest[tid >> 6] = best; widx[tid >> 6] = bidx; }
    __syncthreads();

    if (tid == 0) {
        best = wbest[0]; bidx = widx[0];
        #pragma unroll
        for (int w = 1; w < 4; ++w) {
            if (wbest[w] < best || (wbest[w] == best && widx[w] < bidx)) {
                best = wbest[w]; bidx = widx[w];
            }
        }
        float dx = xi - sx[bidx], dy = yi - sy[bidx], dz = zi - sz[bidx];
        float d  = sqrtf(dx * dx + dy * dy + dz * dz);
        atomicAdd(out, tanhf(d) * (1.0f / (float)NC));
    }
}

extern "C" void kernel_launch(void* const* d_in, const int* in_sizes, int n_in,
                              void* d_out, int out_size, void* d_ws, size_t ws_size,
                              hipStream_t stream) {
    const int*   pc    = (const int*)d_in[0];    // presented_contact [1024] int32
    const float* verts = (const float*)d_in[1];  // vertices [1,6890,3] f32
    const void*  gm    = d_in[2];                // geomask [6890,6890] bool (storage detected)
    float*       out   = (float*)d_out;          // scalar f32 loss

    hipMemsetAsync(out, 0, sizeof(float), stream);          // graph-capture-safe
    contact_row_kernel<<<NC, 256, 0, stream>>>(pc, verts, gm, out);
}